// Round 5
// baseline (295.401 us; speedup 1.0000x reference)
//
#include <hip/hip_runtime.h>
#include <math.h>

#define B_ 8
#define L_ 200
#define H_ 128
#define NH_ 2
#define HD_ 64
#define LP_ 256   // padded L (pad region never zeroed; OOB contributions discarded)
#define TV_ 32    // time vocab
#define NBLK_ (B_ * (L_ / 2))   // 800 blocks; all co-resident (verified round 4)
#define NPROD_ (L_ / 2)         // producers per batch = 100

// ---------------- single fused kernel (per-batch counter dependency) ----------------
// grid = 800 blocks x 256 threads (4 waves), co-resident by construction
// (__launch_bounds__(256,4); VGPR=56, LDS=8.7KB measured round 4 -> no limit binds).
// Phase 0: this block's 2 rows -> Q (LDS), K^T + kpos, V + vpos (workspace);
//          thread 0: cnt[b] += 1 (RELEASE, agent).
// Wait:    thread 0 polls cnt[b] ACQUIRE + s_sleep until ==100 (single poller per
//          block, ~0.2us period -> no invalidate storm, unlike round 4's 100-thread
//          tight acquire spin); then barrier + per-thread __threadfence() (the
//          round-4-validated coherence sequence for cross-XCD K/V reads).
// Phase 1: attention + time-attn + out-proj + residual + LayerNorm (unchanged).
__global__ __launch_bounds__(256, 4)
void fused_kernel(const float* __restrict__ X,
                  const float* __restrict__ Wq, const float* __restrict__ bq,
                  const float* __restrict__ Wk, const float* __restrict__ bk,
                  const float* __restrict__ Wv, const float* __restrict__ bv,
                  const float* __restrict__ kpt, const float* __restrict__ vpt,
                  const int*   __restrict__ tseq, const float* __restrict__ mask,
                  const float* __restrict__ ktt, const float* __restrict__ vtt,
                  const float* __restrict__ Wd,  const float* __restrict__ bd,
                  const float* __restrict__ g,   const float* __restrict__ bb,
                  float* Kt, float* Vp, unsigned* cnt, float* __restrict__ out){
    const int b  = blockIdx.x / (L_ / 2);
    const int q0 = (blockIdx.x % (L_ / 2)) * 2;

    __shared__ __align__(16) float qs   [2][2][HD_];   // Q stays on-chip
    __shared__ __align__(16) float xs   [2][H_];
    __shared__ float qkt_s[4][TV_];
    __shared__ float ss_s [4][TV_];
    __shared__ __align__(16) float ps_s [4][LP_];
    __shared__ __align__(16) float ctx_s[2][H_];
    __shared__ float redA[4], redB[4];

    // ---- phase 0: QKV projection for rows q0, q0+1 (thread j: r=j>>7, c=j&127)
    {
        const int j = threadIdx.x, r = j >> 7, c = j & 127;
        xs[r][c] = X[(b * L_ + q0 + r) * H_ + c];
        __syncthreads();
        float aq = 0.f, ak = 0.f, av = 0.f;
        const float4* xv4 = (const float4*)xs[r];
        #pragma unroll 2
        for (int i4 = 0; i4 < H_ / 4; ++i4) {
            const float4 xv = xv4[i4];
            const int i = i4 * 4;
            aq += xv.x * Wq[(i + 0) * H_ + c] + xv.y * Wq[(i + 1) * H_ + c]
                + xv.z * Wq[(i + 2) * H_ + c] + xv.w * Wq[(i + 3) * H_ + c];
            ak += xv.x * Wk[(i + 0) * H_ + c] + xv.y * Wk[(i + 1) * H_ + c]
                + xv.z * Wk[(i + 2) * H_ + c] + xv.w * Wk[(i + 3) * H_ + c];
            av += xv.x * Wv[(i + 0) * H_ + c] + xv.y * Wv[(i + 1) * H_ + c]
                + xv.z * Wv[(i + 2) * H_ + c] + xv.w * Wv[(i + 3) * H_ + c];
        }
        const int h = c >> 6, d = c & 63, l = q0 + r;
        qs[r][h][d] = aq + bq[c];                                     // LDS only
        Kt[((b * NH_ + h) * HD_ + d) * LP_ + l] = ak + bk[c] + kpt[l * H_ + c];
        Vp[((b * NH_ + h) * L_ + l) * HD_ + d]  = av + bv[c] + vpt[l * H_ + c];
    }
    __syncthreads();   // all K/V stores of this block drained (vmcnt0 before barrier)
    if (threadIdx.x == 0) {
        // release: this block's K/V visible before the count ticks
        __hip_atomic_fetch_add(&cnt[b], 1u, __ATOMIC_RELEASE, __HIP_MEMORY_SCOPE_AGENT);
        // single-poller wait: ~0.2us period, 1 poll-load per block per period
        while (__hip_atomic_load(&cnt[b], __ATOMIC_ACQUIRE,
                                 __HIP_MEMORY_SCOPE_AGENT) < (unsigned)NPROD_)
            __builtin_amdgcn_s_sleep(8);
    }
    __syncthreads();
    __threadfence();   // acquire side for ALL threads (round-4-validated sequence)

    // ---- phase 1: attention. wave w: head h = w&1, q-row qr = w>>1.
    const int w = threadIdx.x >> 6, lane = threadIdx.x & 63;
    const int h = w & 1, qr = w >> 1;
    const int q = q0 + qr;
    const int bh = b * NH_ + h;

    if (lane < TV_) ss_s[w][lane] = 0.f;   // wave-private

    // qkt[bkt] = dot(q, ktt[bkt, head slice]); 2 lanes per bucket, from L2
    {
        const int bkt = lane >> 1, half = lane & 1;
        const float4* kr4  = (const float4*)(ktt + bkt * H_ + h * HD_ + half * 32);
        const float4* qv4p = (const float4*)(&qs[qr][h][half * 32]);
        float a = 0.f;
        #pragma unroll
        for (int d4 = 0; d4 < 8; ++d4) {
            const float4 kv = kr4[d4];
            const float4 qv = qv4p[d4];
            a += qv.x * kv.x + qv.y * kv.y + qv.z * kv.z + qv.w * kv.w;
        }
        a += __shfl_xor(a, 1);
        if (half == 0) qkt_s[w][bkt] = a;   // same-wave LDS, ordered
    }

    // ---- phase A: lane handles k = 4*lane .. 4*lane+3
    const float4* kt4 = (const float4*)(Kt + (size_t)bh * HD_ * LP_);
    const float4* qv4 = (const float4*)qs[qr][h];
    float4 s4 = make_float4(0.f, 0.f, 0.f, 0.f);
    #pragma unroll 4
    for (int d4 = 0; d4 < HD_ / 4; ++d4) {
        const float4 qq = qv4[d4];
        const float4 k0 = kt4[(d4 * 4 + 0) * (LP_ / 4) + lane];
        const float4 k1 = kt4[(d4 * 4 + 1) * (LP_ / 4) + lane];
        const float4 k2 = kt4[(d4 * 4 + 2) * (LP_ / 4) + lane];
        const float4 k3 = kt4[(d4 * 4 + 3) * (LP_ / 4) + lane];
        s4.x += qq.x * k0.x + qq.y * k1.x + qq.z * k2.x + qq.w * k3.x;
        s4.y += qq.x * k0.y + qq.y * k1.y + qq.z * k2.y + qq.w * k3.y;
        s4.z += qq.x * k0.z + qq.y * k1.z + qq.z * k2.z + qq.w * k3.z;
        s4.w += qq.x * k0.w + qq.y * k1.w + qq.z * k2.w + qq.w * k3.w;
    }
    float sv[4] = {s4.x, s4.y, s4.z, s4.w};
    const int k0i = lane * 4;
    float mx = -INFINITY;
    if (k0i < L_) {  // lanes 0..49; rows 800B-aligned -> float4/int4 ok
        const float4 m4 = ((const float4*)(mask + ((size_t)(b * L_ + q)) * L_))[lane];
        const int4   t4 = ((const int4*)(tseq + b * L_))[lane];
        const int    tq = tseq[b * L_ + q];
        const float mv[4] = {m4.x, m4.y, m4.z, m4.w};
        const int   tk[4] = {t4.x, t4.y, t4.z, t4.w};
        #pragma unroll
        for (int jj = 0; jj < 4; ++jj) {
            int dt = tq - tk[jj]; if (dt < 0) dt = -dt;
            int ib = (int)log1pf((float)dt); if (ib > TV_ - 1) ib = TV_ - 1;
            const float s = (sv[jj] + qkt_s[w][ib]) * 0.125f + mv[jj];
            sv[jj] = s;
            atomicAdd(&ss_s[w][ib], s);     // pre-softmax bucket sums (wave-private)
            if (s > mx) mx = s;
        }
    } else {
        sv[0] = sv[1] = sv[2] = sv[3] = -INFINITY;  // Kt pad garbage discarded
    }
    #pragma unroll
    for (int off = 32; off; off >>= 1) { const float o = __shfl_xor(mx, off); if (o > mx) mx = o; }
    float sum = 0.f, ev[4];
    #pragma unroll
    for (int jj = 0; jj < 4; ++jj) {
        const float e = (k0i + jj < L_) ? __expf(sv[jj] - mx) : 0.f;
        ev[jj] = e; sum += e;
    }
    #pragma unroll
    for (int off = 32; off; off >>= 1) sum += __shfl_xor(sum, off);
    ((float4*)ps_s[w])[lane] = make_float4(ev[0], ev[1], ev[2], ev[3]);
    const float inv = 1.f / sum;

    // ---- phase B (PV): lane = (kk = k-group, d4 = d-quad); float4 V loads
    {
        const int kk = lane >> 4, d4 = lane & 15;
        const float4* vp4 = (const float4*)(Vp + (size_t)bh * L_ * HD_);
        float4 c4 = make_float4(0.f, 0.f, 0.f, 0.f);
        #pragma unroll 5
        for (int kb = 0; kb < L_; kb += 4) {
            const float  p  = ps_s[w][kb + kk];               // same-wave LDS, ordered
            const float4 vv = vp4[(kb + kk) * (HD_ / 4) + d4];
            c4.x += p * vv.x; c4.y += p * vv.y; c4.z += p * vv.z; c4.w += p * vv.w;
        }
        #pragma unroll
        for (int off = 16; off <= 32; off <<= 1) {            // butterfly over kk
            c4.x += __shfl_xor(c4.x, off);
            c4.y += __shfl_xor(c4.y, off);
            c4.z += __shfl_xor(c4.z, off);
            c4.w += __shfl_xor(c4.w, off);
        }
        if (kk == 0) {
            c4.x *= inv; c4.y *= inv; c4.z *= inv; c4.w *= inv;
            *(float4*)&ctx_s[qr][h * HD_ + d4 * 4] = c4;
        }
    }
    // time-ctx: lane = d, vtt straight from L2; raw pre-softmax scores
    {
        float tc = 0.f;
        #pragma unroll 8
        for (int i = 0; i < TV_; ++i) tc += ss_s[w][i] * vtt[i * H_ + h * HD_ + lane];
        ctx_s[qr][h * HD_ + lane] += tc;   // same-wave LDS after float4 store: ordered
    }
    __syncthreads();   // join: out-proj reads full ctx rows across waves

    // ---- out projection + residual + one-pass LayerNorm: 1 row per 128 thr
    const int rr = threadIdx.x >> 7, j = threadIdx.x & 127;
    const float4* cr = (const float4*)ctx_s[rr];
    float acc = 0.f;
    #pragma unroll 8
    for (int i4 = 0; i4 < H_ / 4; ++i4) {
        const float4 xa = cr[i4];
        const int i = i4 * 4;
        acc += xa.x * Wd[(i + 0) * H_ + j];
        acc += xa.y * Wd[(i + 1) * H_ + j];
        acc += xa.z * Wd[(i + 2) * H_ + j];
        acc += xa.w * Wd[(i + 3) * H_ + j];
    }
    const int row = b * L_ + q0 + rr;
    const float x = acc + bd[j] + xs[rr][j];       // residual from LDS copy of X
    float s1 = x, s2 = x * x;
    #pragma unroll
    for (int off = 32; off; off >>= 1) { s1 += __shfl_xor(s1, off); s2 += __shfl_xor(s2, off); }
    if (lane == 0) { redA[w] = s1; redB[w] = s2; }
    __syncthreads();
    const float mean = (redA[2 * rr] + redA[2 * rr + 1]) * (1.f / H_);
    const float ex2  = (redB[2 * rr] + redB[2 * rr + 1]) * (1.f / H_);
    const float var  = ex2 - mean * mean;
    out[row * H_ + j] = (x - mean) * rsqrtf(var + 1e-12f) * g[j] + bb[j];
}

// ---------------------------------------------------------------- launch
extern "C" void kernel_launch(void* const* d_in, const int* in_sizes, int n_in,
                              void* d_out, int out_size, void* d_ws, size_t ws_size,
                              hipStream_t stream) {
    const float* X    = (const float*)d_in[0];
    const int*   tseq = (const int*)  d_in[1];
    const float* mask = (const float*)d_in[2];
    const float* Wq = (const float*)d_in[3],  *bq = (const float*)d_in[4];
    const float* Wk = (const float*)d_in[5],  *bk = (const float*)d_in[6];
    const float* Wv = (const float*)d_in[7],  *bv = (const float*)d_in[8];
    const float* Wd = (const float*)d_in[9],  *bd = (const float*)d_in[10];
    const float* g  = (const float*)d_in[11], *bb = (const float*)d_in[12];
    const float* ktt = (const float*)d_in[13], *vtt = (const float*)d_in[14];
    const float* kpt = (const float*)d_in[15], *vpt = (const float*)d_in[16];

    float*    ws  = (float*)d_ws;
    float*    Kt  = ws;                          // B*NH*HD*LP = 262144 floats
    float*    Vp  = Kt + B_ * NH_ * HD_ * LP_;   // B*L*H      = 204800 floats
    unsigned* cnt = (unsigned*)(Vp + B_ * L_ * H_);  // 8 per-batch counters

    // zero the counters (graph-capturable memset node; 32 bytes)
    hipMemsetAsync(cnt, 0, B_ * sizeof(unsigned), stream);

    fused_kernel<<<NBLK_, 256, 0, stream>>>(X, Wq, bq, Wk, bk, Wv, bv, kpt, vpt,
                                            tseq, mask, ktt, vtt, Wd, bd, g, bb,
                                            Kt, Vp, cnt, (float*)d_out);
}

// Round 6
// 118.803 us; speedup vs baseline: 2.4865x; 2.4865x over previous
//
#include <hip/hip_runtime.h>
#include <math.h>

#define B_ 8
#define L_ 200
#define H_ 128
#define NH_ 2
#define HD_ 64
#define LP_ 256   // padded L (pad region never zeroed; OOB contributions discarded)
#define TV_ 32    // time vocab
#define RQ_ 8     // rows per qkv block

// ---------------------------------------------------------------- fused QKV
// grid (B*L/RQ_, 3), 128 threads; m = 0:Q, 1:K(transposed), 2:V
__global__ __launch_bounds__(128)
void qkv_kernel(const float* __restrict__ X,
                const float* __restrict__ Wq, const float* __restrict__ bq,
                const float* __restrict__ Wk, const float* __restrict__ bk,
                const float* __restrict__ Wv, const float* __restrict__ bv,
                const float* __restrict__ kpt, const float* __restrict__ vpt,
                float* __restrict__ Q, float* __restrict__ Kt, float* __restrict__ Vp){
    const int r0 = blockIdx.x * RQ_;
    const int m  = blockIdx.y;
    const int j  = threadIdx.x;
    __shared__ float xs[RQ_][H_];
    #pragma unroll
    for (int r = 0; r < RQ_; ++r) xs[r][j] = X[(r0 + r) * H_ + j];
    __syncthreads();
    const float* W = (m == 0) ? Wq : ((m == 1) ? Wk : Wv);
    float acc[RQ_];
    #pragma unroll
    for (int r = 0; r < RQ_; ++r) acc[r] = 0.f;
    #pragma unroll 8
    for (int i = 0; i < H_; ++i) {
        const float w = W[i * H_ + j];
        #pragma unroll
        for (int r = 0; r < RQ_; ++r) acc[r] += xs[r][i] * w;
    }
    const int h = j >> 6, d = j & 63;
    if (m == 0) {
        const float bj = bq[j];
        #pragma unroll
        for (int r = 0; r < RQ_; ++r) Q[(r0 + r) * H_ + j] = acc[r] + bj;
    } else if (m == 1) {
        const float bj = bk[j];
        #pragma unroll
        for (int r = 0; r < RQ_; ++r) {
            const int row = r0 + r, b = row / L_, l = row % L_;
            Kt[((b * NH_ + h) * HD_ + d) * LP_ + l] = acc[r] + bj + kpt[l * H_ + j];
        }
    } else {
        const float bj = bv[j];
        #pragma unroll
        for (int r = 0; r < RQ_; ++r) {
            const int row = r0 + r, b = row / L_, l = row % L_;
            Vp[((b * NH_ + h) * L_ + l) * HD_ + d] = acc[r] + bj + vpt[l * H_ + j];
        }
    }
}

// ------------------------------------------- fused attention + out-proj + LN
// grid = B * (L/4) = 400 blocks of 256 threads (4 waves).
// wave w: head h = w&1, q-pair qp = w>>1 -> q rows {q0+2qp, q0+2qp+1}.
__global__ __launch_bounds__(256)
void attn_out_kernel(const float* __restrict__ Q, const float* __restrict__ Kt,
                     const float* __restrict__ Vp, const int* __restrict__ tseq,
                     const float* __restrict__ mask,
                     const float* __restrict__ ktt, const float* __restrict__ vtt,
                     const float* __restrict__ Wd, const float* __restrict__ bd,
                     const float* __restrict__ X, const float* __restrict__ g,
                     const float* __restrict__ bb, float* __restrict__ out){
    const int b  = blockIdx.x / (L_ / 4);
    const int q0 = (blockIdx.x % (L_ / 4)) * 4;
    const int w  = threadIdx.x >> 6, lane = threadIdx.x & 63;
    const int h  = w & 1, qp = w >> 1;
    const int qa = q0 + 2 * qp, qb = qa + 1;
    const int bh = b * NH_ + h;

    __shared__ float ktt_s[TV_][H_ + 1];   // +1 pad: qkt access conflict-free
    __shared__ float vtt_s[TV_][H_ + 1];
    __shared__ __align__(16) float qs [4][2][HD_];
    __shared__ __align__(16) float qkt[4][2][TV_];
    __shared__ __align__(16) float ss [4][2][TV_];
    __shared__ __align__(16) float ps [4][2][LP_];
    __shared__ __align__(16) float ctx_s[4][H_];
    __shared__ float redA[4], redB[4], red2A[4], red2B[4];

    // coalesced table staging (16.5 KB x2)
    for (int t = threadIdx.x; t < TV_ * H_; t += 256) {
        ktt_s[t >> 7][t & 127] = ktt[t];
        vtt_s[t >> 7][t & 127] = vtt[t];
    }
    qs[w][0][lane] = Q[(b * L_ + qa) * H_ + h * HD_ + lane];
    qs[w][1][lane] = Q[(b * L_ + qb) * H_ + h * HD_ + lane];
    ss[w][lane >> 5][lane & 31] = 0.f;
    __syncthreads();

    // qkt[q][i] = dot(q_vec, ktt[i, head slice]); lane = (q-sel<<5)|bucket
    {
        const int i = lane & 31, qsel = lane >> 5;
        float a = 0.f;
        #pragma unroll 8
        for (int d = 0; d < HD_; ++d)
            a += qs[w][qsel][d] * ktt_s[i][h * HD_ + d];
        qkt[w][qsel][i] = a;
    }

    // ---- phase A: lane handles k = 4*lane .. 4*lane+3, for both q's
    const float4* kt4 = (const float4*)(Kt + (size_t)bh * HD_ * LP_);
    float4 sa = make_float4(0.f, 0.f, 0.f, 0.f);
    float4 sb = make_float4(0.f, 0.f, 0.f, 0.f);
    #pragma unroll 8
    for (int d = 0; d < HD_; ++d) {
        const float4 kv = kt4[d * (LP_ / 4) + lane];
        const float qad = qs[w][0][d], qbd = qs[w][1][d];
        sa.x += qad * kv.x; sa.y += qad * kv.y; sa.z += qad * kv.z; sa.w += qad * kv.w;
        sb.x += qbd * kv.x; sb.y += qbd * kv.y; sb.z += qbd * kv.z; sb.w += qbd * kv.w;
    }
    float sva[4] = {sa.x, sa.y, sa.z, sa.w};
    float svb[4] = {sb.x, sb.y, sb.z, sb.w};
    const int k0i = lane * 4;
    float mxa = -INFINITY, mxb = -INFINITY;
    if (k0i < L_) {  // lanes 0..49; rows 800B-aligned -> float4/int4 ok
        const float4 m4a = ((const float4*)(mask + ((size_t)(b * L_ + qa)) * L_))[lane];
        const float4 m4b = ((const float4*)(mask + ((size_t)(b * L_ + qb)) * L_))[lane];
        const int4   t4  = ((const int4*)(tseq + b * L_))[lane];
        const int    tqa = tseq[b * L_ + qa], tqb = tseq[b * L_ + qb];
        const float mva[4] = {m4a.x, m4a.y, m4a.z, m4a.w};
        const float mvb[4] = {m4b.x, m4b.y, m4b.z, m4b.w};
        const int   tk[4]  = {t4.x, t4.y, t4.z, t4.w};
        #pragma unroll
        for (int jj = 0; jj < 4; ++jj) {
            int dta = tqa - tk[jj]; if (dta < 0) dta = -dta;
            int dtb = tqb - tk[jj]; if (dtb < 0) dtb = -dtb;
            int ia = (int)log1pf((float)dta); if (ia > TV_ - 1) ia = TV_ - 1;
            int ib = (int)log1pf((float)dtb); if (ib > TV_ - 1) ib = TV_ - 1;
            float s_a = (sva[jj] + qkt[w][0][ia]) * 0.125f + mva[jj];
            float s_b = (svb[jj] + qkt[w][1][ib]) * 0.125f + mvb[jj];
            sva[jj] = s_a; svb[jj] = s_b;
            atomicAdd(&ss[w][0][ia], s_a);     // pre-softmax bucket sums
            atomicAdd(&ss[w][1][ib], s_b);
            if (s_a > mxa) mxa = s_a;
            if (s_b > mxb) mxb = s_b;
        }
    } else {
        sva[0] = sva[1] = sva[2] = sva[3] = -INFINITY;
        svb[0] = svb[1] = svb[2] = svb[3] = -INFINITY;
    }
    // wave-wide softmax (both q's)
    for (int off = 32; off; off >>= 1) {
        float oa = __shfl_xor(mxa, off); if (oa > mxa) mxa = oa;
        float ob = __shfl_xor(mxb, off); if (ob > mxb) mxb = ob;
    }
    float suma = 0.f, sumb = 0.f, eva[4], evb[4];
    #pragma unroll
    for (int jj = 0; jj < 4; ++jj) {
        float ea = (k0i + jj < L_) ? __expf(sva[jj] - mxa) : 0.f;
        float eb = (k0i + jj < L_) ? __expf(svb[jj] - mxb) : 0.f;
        eva[jj] = ea; suma += ea;
        evb[jj] = eb; sumb += eb;
    }
    for (int off = 32; off; off >>= 1) { suma += __shfl_xor(suma, off); sumb += __shfl_xor(sumb, off); }
    ((float4*)ps[w][0])[lane] = make_float4(eva[0], eva[1], eva[2], eva[3]);
    ((float4*)ps[w][1])[lane] = make_float4(evb[0], evb[1], evb[2], evb[3]);

    // ---- phase B: lane = d (ps/ss same-wave LDS, ordered)
    const float inva = 1.f / suma, invb = 1.f / sumb;
    const float* vp = Vp + (size_t)bh * L_ * HD_;
    const float4* psa4 = (const float4*)ps[w][0];
    const float4* psb4 = (const float4*)ps[w][1];
    float ca = 0.f, cb = 0.f;
    #pragma unroll 5
    for (int k4 = 0; k4 < L_ / 4; ++k4) {
        const float4 pa = psa4[k4], pb = psb4[k4];
        const int kb = k4 * 4;
        const float v0 = vp[(kb + 0) * HD_ + lane];
        const float v1 = vp[(kb + 1) * HD_ + lane];
        const float v2 = vp[(kb + 2) * HD_ + lane];
        const float v3 = vp[(kb + 3) * HD_ + lane];
        ca += pa.x * v0; ca += pa.y * v1; ca += pa.z * v2; ca += pa.w * v3;
        cb += pb.x * v0; cb += pb.y * v1; cb += pb.z * v2; cb += pb.w * v3;
    }
    ca *= inva; cb *= invb;
    float tca = 0.f, tcb = 0.f;
    const float4* ssa4 = (const float4*)ss[w][0];
    const float4* ssb4 = (const float4*)ss[w][1];
    #pragma unroll
    for (int i4 = 0; i4 < TV_ / 4; ++i4) {
        const float4 za = ssa4[i4], zb = ssb4[i4];
        const int i = i4 * 4;
        const float w0 = vtt_s[i + 0][h * HD_ + lane];
        const float w1 = vtt_s[i + 1][h * HD_ + lane];
        const float w2 = vtt_s[i + 2][h * HD_ + lane];
        const float w3 = vtt_s[i + 3][h * HD_ + lane];
        tca += za.x * w0; tca += za.y * w1; tca += za.z * w2; tca += za.w * w3;
        tcb += zb.x * w0; tcb += zb.y * w1; tcb += zb.z * w2; tcb += zb.w * w3;
    }
    ctx_s[2 * qp + 0][h * HD_ + lane] = ca + tca;
    ctx_s[2 * qp + 1][h * HD_ + lane] = cb + tcb;
    __syncthreads();

    // ---- out projection + residual + LayerNorm: 4 rows, 2 per thread
    const int r = threadIdx.x >> 7, j = threadIdx.x & 127;   // rows r and r+2
    const float4* ca4 = (const float4*)ctx_s[r];
    const float4* cb4 = (const float4*)ctx_s[r + 2];
    float acc_a = 0.f, acc_b = 0.f;
    #pragma unroll 8
    for (int i4 = 0; i4 < H_ / 4; ++i4) {
        const float4 xa = ca4[i4], xb = cb4[i4];
        const int i = i4 * 4;
        const float w0 = Wd[(i + 0) * H_ + j];
        const float w1 = Wd[(i + 1) * H_ + j];
        const float w2 = Wd[(i + 2) * H_ + j];
        const float w3 = Wd[(i + 3) * H_ + j];
        acc_a += xa.x * w0; acc_a += xa.y * w1; acc_a += xa.z * w2; acc_a += xa.w * w3;
        acc_b += xb.x * w0; acc_b += xb.y * w1; acc_b += xb.z * w2; acc_b += xb.w * w3;
    }
    const int rowa = b * L_ + q0 + r, rowb = rowa + 2;
    const float bdj = bd[j];
    const float x_a = acc_a + bdj + X[rowa * H_ + j];
    const float x_b = acc_b + bdj + X[rowb * H_ + j];

    float s1a = x_a, s1b = x_b;
    for (int off = 32; off; off >>= 1) { s1a += __shfl_xor(s1a, off); s1b += __shfl_xor(s1b, off); }
    if (lane == 0) { redA[w] = s1a; redB[w] = s1b; }
    __syncthreads();
    const float meanA = (redA[2 * r] + redA[2 * r + 1]) * (1.f / H_);
    const float meanB = (redB[2 * r] + redB[2 * r + 1]) * (1.f / H_);
    const float dxa = x_a - meanA, dxb = x_b - meanB;
    float s2a = dxa * dxa, s2b = dxb * dxb;
    for (int off = 32; off; off >>= 1) { s2a += __shfl_xor(s2a, off); s2b += __shfl_xor(s2b, off); }
    if (lane == 0) { red2A[w] = s2a; red2B[w] = s2b; }
    __syncthreads();
    const float varA = (red2A[2 * r] + red2A[2 * r + 1]) * (1.f / H_);
    const float varB = (red2B[2 * r] + red2B[2 * r + 1]) * (1.f / H_);
    const float gj = g[j], bbj = bb[j];
    out[rowa * H_ + j] = dxa * rsqrtf(varA + 1e-12f) * gj + bbj;
    out[rowb * H_ + j] = dxb * rsqrtf(varB + 1e-12f) * gj + bbj;
}

// ---------------------------------------------------------------- launch
extern "C" void kernel_launch(void* const* d_in, const int* in_sizes, int n_in,
                              void* d_out, int out_size, void* d_ws, size_t ws_size,
                              hipStream_t stream) {
    const float* X    = (const float*)d_in[0];
    const int*   tseq = (const int*)  d_in[1];
    const float* mask = (const float*)d_in[2];
    const float* Wq = (const float*)d_in[3],  *bq = (const float*)d_in[4];
    const float* Wk = (const float*)d_in[5],  *bk = (const float*)d_in[6];
    const float* Wv = (const float*)d_in[7],  *bv = (const float*)d_in[8];
    const float* Wd = (const float*)d_in[9],  *bd = (const float*)d_in[10];
    const float* g  = (const float*)d_in[11], *bb = (const float*)d_in[12];
    const float* ktt = (const float*)d_in[13], *vtt = (const float*)d_in[14];
    const float* kpt = (const float*)d_in[15], *vpt = (const float*)d_in[16];

    float* ws  = (float*)d_ws;
    float* Q   = ws;                          // B*L*H      = 204800
    float* Kt  = Q   + B_ * L_ * H_;          // B*NH*HD*LP = 262144 (pad unzeroed, by design)
    float* Vp  = Kt  + B_ * NH_ * HD_ * LP_;  // B*L*H      = 204800

    dim3 g1(B_ * L_ / RQ_, 3);
    qkv_kernel<<<g1, 128, 0, stream>>>(X, Wq, bq, Wk, bk, Wv, bv, kpt, vpt, Q, Kt, Vp);
    attn_out_kernel<<<B_ * (L_ / 4), 256, 0, stream>>>(Q, Kt, Vp, tseq, mask, ktt, vtt,
                                                       Wd, bd, X, g, bb, (float*)d_out);
}